// Round 1
// baseline (632.693 us; speedup 1.0000x reference)
//
#include <hip/hip_runtime.h>
#include <math.h>

#define NB   16
#define NQ   4096
#define NTGT 128
#define CELEMS (NB * NQ * NTGT)

#define BT 512
#define NW (BT / 64)

// ---------------- cost matrix kernel ----------------
__global__ __launch_bounds__(256) void cost_kernel(
    const float* __restrict__ outputs,
    const float* __restrict__ targets,
    float* __restrict__ C)
{
    int idx = blockIdx.x * 256 + threadIdx.x;           // [0, NB*NQ*NTGT)
    int t   = idx & (NTGT - 1);
    int bq  = idx >> 7;                                 // b*NQ + q
    int b   = idx >> 19;                                // /(NQ*NTGT)
    float4 o = reinterpret_cast<const float4*>(outputs)[bq];
    float4 g = reinterpret_cast<const float4*>(targets)[(b << 7) + t];
    float c = ((fabsf(o.x - g.x) + fabsf(o.y - g.y)) + fabsf(o.z - g.z)) + fabsf(o.w - g.w);
    C[idx] = c;
}

// ---------------- LSA (Jonker-Volgenant) kernel ----------------
// One block per batch. Solves the transposed problem: 128 rows (targets),
// 4096 cols (queries), replicating the reference numpy implementation in
// float64 with identical op ordering and argmin tie-breaking.
__global__ __launch_bounds__(BT, 1) void lsa_kernel(
    const float* __restrict__ outputs,
    const float* __restrict__ targets,
    float* __restrict__ row_out,   // [NB, NTGT] as float
    float* __restrict__ col_out)   // [NB, NTGT] as float
{
    __shared__ double v_[NQ];            // 32 KB
    __shared__ double shortest_[NQ];     // 32 KB
    __shared__ double u_[NTGT];
    __shared__ float4 tgt_[NTGT];
    __shared__ unsigned char remaining_[NQ];
    __shared__ unsigned char SC_[NQ];
    __shared__ unsigned char SR_[NTGT];
    __shared__ unsigned char path_[NQ];  // row index < 128 fits in u8
    __shared__ short row4col_[NQ];
    __shared__ short col4row_[NTGT];
    __shared__ double red_val[NW];
    __shared__ int    red_idx[NW];
    __shared__ double s_minval;
    __shared__ int    s_i;
    __shared__ int    s_sink;

    const int tid = threadIdx.x;
    const int b   = blockIdx.x;
    const float4* outq = reinterpret_cast<const float4*>(outputs) + b * NQ;

    // one-time init
    for (int k = tid; k < NQ; k += BT) { v_[k] = 0.0; row4col_[k] = -1; }
    for (int k = tid; k < NTGT; k += BT) {
        u_[k] = 0.0; col4row_[k] = -1;
        tgt_[k] = reinterpret_cast<const float4*>(targets)[b * NTGT + k];
    }
    __syncthreads();

    for (int cur = 0; cur < NTGT; ++cur) {
        // per-row init
        for (int k = tid; k < NQ; k += BT) {
            shortest_[k] = (double)INFINITY;
            remaining_[k] = 1;
            SC_[k] = 0;
        }
        for (int k = tid; k < NTGT; k += BT) SR_[k] = 0;
        if (tid == 0) { s_i = cur; s_minval = 0.0; s_sink = -1; }
        __syncthreads();

        // Dijkstra / shortest augmenting path
        while (true) {
            const int    i    = s_i;
            const double minv = s_minval;
            const double ui   = u_[i];
            const float4 g    = tgt_[i];
            if (tid == 0) SR_[i] = 1;

            double bv = (double)INFINITY;
            int    bi = 0x7fffffff;
            for (int k = tid; k < NQ; k += BT) {
                if (remaining_[k]) {
                    float4 o = outq[k];
                    float  c = ((fabsf(o.x - g.x) + fabsf(o.y - g.y)) + fabsf(o.z - g.z)) + fabsf(o.w - g.w);
                    double cand = ((minv + (double)c) - ui) - v_[k];
                    if (cand < shortest_[k]) {
                        shortest_[k] = cand;
                        path_[k] = (unsigned char)i;
                    }
                    double s = shortest_[k];
                    if (s < bv) { bv = s; bi = k; }  // strict < keeps lowest index
                }
            }
            // wave-level (min, lowest-index) reduction
            for (int off = 32; off > 0; off >>= 1) {
                double ov = __shfl_down(bv, off);
                int    oi = __shfl_down(bi, off);
                if (ov < bv || (ov == bv && oi < bi)) { bv = ov; bi = oi; }
            }
            if ((tid & 63) == 0) { red_val[tid >> 6] = bv; red_idx[tid >> 6] = bi; }
            __syncthreads();
            if (tid == 0) {
                double fv = red_val[0]; int fi = red_idx[0];
                for (int w = 1; w < NW; ++w) {
                    double ov = red_val[w]; int oi = red_idx[w];
                    if (ov < fv || (ov == fv && oi < fi)) { fv = ov; fi = oi; }
                }
                int j = fi;
                s_minval = shortest_[j];
                SC_[j] = 1;
                remaining_[j] = 0;
                int r = row4col_[j];
                if (r < 0) s_sink = j; else s_i = r;
            }
            __syncthreads();
            if (s_sink >= 0) break;
        }

        // dual updates (exactly reference order of ops)
        const double minv = s_minval;
        const int    sink = s_sink;
        for (int k = tid; k < NTGT; k += BT) {
            if (SR_[k]) {
                if (k == cur) u_[k] += minv;
                else          u_[k] += minv - shortest_[col4row_[k]];
            }
        }
        for (int k = tid; k < NQ; k += BT) {
            if (SC_[k]) v_[k] -= minv - shortest_[k];
        }
        __syncthreads();

        // augment along alternating path (serial, short)
        if (tid == 0) {
            int j = sink;
            while (true) {
                int i2 = path_[j];
                row4col_[j] = (short)i2;
                int nj = col4row_[i2];
                col4row_[i2] = (short)j;
                j = nj;
                if (i2 == cur) break;
            }
        }
        __syncthreads();
    }

    // outputs (transposed case): order = argsort(col4row);
    // row_ind = col4row[order]; col_ind = order. All values distinct ->
    // rank by counting smaller values (O(128^2), trivial).
    if (tid < NTGT) {
        int val = col4row_[tid];
        int rank = 0;
        for (int k = 0; k < NTGT; ++k) rank += (col4row_[k] < val);
        row_out[b * NTGT + rank] = (float)val;
        col_out[b * NTGT + rank] = (float)tid;
    }
}

extern "C" void kernel_launch(void* const* d_in, const int* in_sizes, int n_in,
                              void* d_out, int out_size, void* d_ws, size_t ws_size,
                              hipStream_t stream) {
    const float* outputs = (const float*)d_in[0];   // [16, 4096, 4]
    const float* targets = (const float*)d_in[1];   // [16, 128, 4]
    float* out = (float*)d_out;                     // C | row_ind | col_ind (as f32)

    hipLaunchKernelGGL(cost_kernel, dim3(CELEMS / 256), dim3(256), 0, stream,
                       outputs, targets, out);
    hipLaunchKernelGGL(lsa_kernel, dim3(NB), dim3(BT), 0, stream,
                       outputs, targets, out + CELEMS, out + CELEMS + NB * NTGT);
}

// Round 2
// 276.921 us; speedup vs baseline: 2.2847x; 2.2847x over previous
//
#include <hip/hip_runtime.h>
#include <math.h>

#define NB   16
#define NQ   4096
#define NTGT 128
#define CELEMS (NB * NQ * NTGT)

#define BT  512
#define NW  (BT / 64)
#define CPT 8              // columns per thread (NQ / BT)

// ---------------- cost matrix kernel ----------------
__global__ __launch_bounds__(256) void cost_kernel(
    const float* __restrict__ outputs,
    const float* __restrict__ targets,
    float* __restrict__ C)
{
    int idx = blockIdx.x * 256 + threadIdx.x;           // [0, NB*NQ*NTGT)
    int t   = idx & (NTGT - 1);
    int bq  = idx >> 7;                                 // b*NQ + q
    int b   = idx >> 19;                                // /(NQ*NTGT)
    float4 o = reinterpret_cast<const float4*>(outputs)[bq];
    float4 g = reinterpret_cast<const float4*>(targets)[(b << 7) + t];
    float c = (fabsf(o.x - g.x) + fabsf(o.y - g.y)) + (fabsf(o.z - g.z) + fabsf(o.w - g.w));
    C[idx] = c;
}

// ---------------- LSA (Jonker-Volgenant) kernel ----------------
// One block per batch, transposed problem: 128 rows (targets) x 4096 cols
// (queries). Replicates the reference numpy implementation in float64 with
// identical op ordering and argmin tie-breaking. Column state (outputs,
// shortest, v, remaining) lives in the OWNING thread's registers
// (thread t owns columns [8t, 8t+8)); one barrier per Dijkstra iteration.
__global__ __launch_bounds__(BT, 1) void lsa_kernel(
    const float* __restrict__ outputs,
    const float* __restrict__ targets,
    float* __restrict__ row_out,   // [NB, NTGT] as float
    float* __restrict__ col_out)   // [NB, NTGT] as float
{
    __shared__ float4 tgt_[NTGT];          // 2 KB
    __shared__ double u_[NTGT];            // 1 KB
    __shared__ short  row4col_[NQ];        // 8 KB
    __shared__ short  col4row_[NTGT];      // 256 B
    __shared__ unsigned char path_[NQ];    // 4 KB
    __shared__ int    sc_j[NQ];            // 16 KB  non-sink picks: column
    __shared__ double sc_v[NQ];            // 32 KB  non-sink picks: shortest[j]
    __shared__ double red_val[2][NW];
    __shared__ int    red_idx[2][NW];

    const int tid  = threadIdx.x;
    const int b    = blockIdx.x;
    const int base = tid * CPT;

    // per-thread register state for owned columns
    float4 o[CPT];
    double sh[CPT];
    double vv[CPT];

    #pragma unroll
    for (int kk = 0; kk < CPT; ++kk) {
        o[kk]  = reinterpret_cast<const float4*>(outputs)[b * NQ + base + kk];
        vv[kk] = 0.0;
    }
    for (int k = tid; k < NQ; k += BT) row4col_[k] = -1;
    if (tid < NTGT) {
        u_[tid] = 0.0;
        col4row_[tid] = -1;
        tgt_[tid] = reinterpret_cast<const float4*>(targets)[b * NTGT + tid];
    }
    __syncthreads();

    int parity = 0;

    for (int cur = 0; cur < NTGT; ++cur) {
        unsigned rem = 0xFFu;
        int    i     = cur;
        bool   first = true;
        int    Lns   = 0;      // non-sink picks this row
        double fv    = 0.0;
        int    fj    = -1;
        double minv  = 0.0;

        while (true) {
            const double ui = u_[i];
            const float4 g  = tgt_[i];

            double bv = (double)INFINITY;
            int    bi = 0x7fffffff;

            if (first) {
                #pragma unroll
                for (int kk = 0; kk < CPT; ++kk) {
                    float4 oo = o[kk];
                    float  c  = (fabsf(oo.x - g.x) + fabsf(oo.y - g.y)) +
                                (fabsf(oo.z - g.z) + fabsf(oo.w - g.w));
                    double cand = ((minv + (double)c) - ui) - vv[kk];
                    sh[kk] = cand;
                    path_[base + kk] = (unsigned char)i;
                    if (cand < bv) { bv = cand; bi = base + kk; }
                }
            } else {
                #pragma unroll
                for (int kk = 0; kk < CPT; ++kk) {
                    if (rem & (1u << kk)) {
                        float4 oo = o[kk];
                        float  c  = (fabsf(oo.x - g.x) + fabsf(oo.y - g.y)) +
                                    (fabsf(oo.z - g.z) + fabsf(oo.w - g.w));
                        double cand = ((minv + (double)c) - ui) - vv[kk];
                        if (cand < sh[kk]) { sh[kk] = cand; path_[base + kk] = (unsigned char)i; }
                        double s = sh[kk];
                        if (s < bv) { bv = s; bi = base + kk; }
                    }
                }
            }

            // wave-level (min, lowest-index) reduction
            for (int off = 32; off > 0; off >>= 1) {
                double ov = __shfl_down(bv, off);
                int    oi = __shfl_down(bi, off);
                if (ov < bv || (ov == bv && oi < bi)) { bv = ov; bi = oi; }
            }
            if ((tid & 63) == 0) { red_val[parity][tid >> 6] = bv; red_idx[parity][tid >> 6] = bi; }
            __syncthreads();

            // all threads finish the reduction redundantly (broadcast reads)
            double fvv = red_val[parity][0];
            int    fjj = red_idx[parity][0];
            #pragma unroll
            for (int w = 1; w < NW; ++w) {
                double ov = red_val[parity][w];
                int    oi = red_idx[parity][w];
                if (ov < fvv || (ov == fvv && oi < fjj)) { fvv = ov; fjj = oi; }
            }
            parity ^= 1;
            fv = fvv; fj = fjj;
            minv = fv;

            // owner removes picked column from remaining
            if ((fj >> 3) == tid) rem &= ~(1u << (fj & 7));

            int r = row4col_[fj];
            if (r < 0) break;                 // sink found
            if (tid == 0) { sc_j[Lns] = fj; sc_v[Lns] = fv; }
            Lns++;
            i = r;
            first = false;
        }

        // ---- dual updates (reference op order) ----
        const double dfin = minv;
        // v[j] -= dfin - shortest[j] for non-sink picks (sink term is exactly 0)
        for (int e = 0; e < Lns; ++e) {
            int j = sc_j[e];
            if ((j >> 3) == tid) {
                double d = dfin - sc_v[e];
                #pragma unroll
                for (int kk = 0; kk < CPT; ++kk)
                    if ((j & 7) == kk) vv[kk] -= d;
            }
        }
        if (tid == 0) {
            u_[cur] += dfin;
            for (int e = 0; e < Lns; ++e) {
                int j  = sc_j[e];
                int i2 = row4col_[j];          // pre-augment, matches reference
                u_[i2] += dfin - sc_v[e];
            }
            // augment along alternating path
            int j = fj;
            while (true) {
                int i2 = path_[j];
                row4col_[j] = (short)i2;
                int nj = col4row_[i2];
                col4row_[i2] = (short)j;
                j = nj;
                if (i2 == cur) break;
            }
        }
        __syncthreads();
    }

    // outputs (transposed case): order = argsort(col4row);
    // row_ind = col4row[order]; col_ind = order. Values distinct -> rank by
    // counting smaller values.
    if (tid < NTGT) {
        int val = col4row_[tid];
        int rank = 0;
        for (int k = 0; k < NTGT; ++k) rank += (col4row_[k] < val);
        row_out[b * NTGT + rank] = (float)val;
        col_out[b * NTGT + rank] = (float)tid;
    }
}

extern "C" void kernel_launch(void* const* d_in, const int* in_sizes, int n_in,
                              void* d_out, int out_size, void* d_ws, size_t ws_size,
                              hipStream_t stream) {
    const float* outputs = (const float*)d_in[0];   // [16, 4096, 4]
    const float* targets = (const float*)d_in[1];   // [16, 128, 4]
    float* out = (float*)d_out;                     // C | row_ind | col_ind (as f32)

    hipLaunchKernelGGL(cost_kernel, dim3(CELEMS / 256), dim3(256), 0, stream,
                       outputs, targets, out);
    hipLaunchKernelGGL(lsa_kernel, dim3(NB), dim3(BT), 0, stream,
                       outputs, targets, out + CELEMS, out + CELEMS + NB * NTGT);
}

// Round 3
// 276.051 us; speedup vs baseline: 2.2919x; 1.0032x over previous
//
#include <hip/hip_runtime.h>
#include <math.h>

#define NB   16
#define NQ   4096
#define NTGT 128
#define CELEMS (NB * NQ * NTGT)

#define BT  512
#define NW  (BT / 64)
#define CPT 8              // columns per thread (NQ / BT)

// ---------------- cost matrix kernel ----------------
// One thread computes 4 consecutive t for one (b,q); float4 store.
__global__ __launch_bounds__(256) void cost_kernel(
    const float* __restrict__ outputs,
    const float* __restrict__ targets,
    float* __restrict__ C)
{
    int idx = blockIdx.x * 256 + threadIdx.x;           // [0, CELEMS/4)
    int t4  = idx & 31;                                 // t block of 4
    int bq  = idx >> 5;
    int b   = idx >> 17;
    float4 o = reinterpret_cast<const float4*>(outputs)[bq];
    const float4* tg = reinterpret_cast<const float4*>(targets) + (b << 7) + (t4 << 2);
    float r[4];
    #pragma unroll
    for (int e = 0; e < 4; ++e) {
        float4 g = tg[e];
        r[e] = (fabsf(o.x - g.x) + fabsf(o.y - g.y)) + (fabsf(o.z - g.z) + fabsf(o.w - g.w));
    }
    reinterpret_cast<float4*>(C)[idx] = make_float4(r[0], r[1], r[2], r[3]);
}

// ---------------- LSA (Jonker-Volgenant) kernel ----------------
// One block per batch, transposed problem: 128 rows (targets) x 4096 cols
// (queries). Bit-exact replication of the reference numpy implementation
// (float64, identical op order, lowest-index argmin ties).
// Column state in owning thread's registers; ONE barrier per Dijkstra
// iteration, NO end-of-row barrier (row-end work overlaps next row's scan).
__global__ __launch_bounds__(BT, 1) void lsa_kernel(
    const float* __restrict__ outputs,
    const float* __restrict__ targets,
    float* __restrict__ row_out,   // [NB, NTGT] as float
    float* __restrict__ col_out)   // [NB, NTGT] as float
{
    __shared__ float4 tgt_[NTGT];              // 2 KB
    __shared__ double u_[NTGT];                // 1 KB
    __shared__ short  row4col_[NQ];            // 8 KB
    __shared__ short  col4row_[NTGT];          // 256 B
    __shared__ unsigned char path_[2][NQ];     // 8 KB (row-parity ping-pong)
    __shared__ int    sc_j[NTGT];              // tid0-only pick list
    __shared__ double sc_v[NTGT];
    __shared__ double red_val[2][NW];          // iteration-parity ping-pong
    __shared__ int    red_idx[2][NW];

    const int tid  = threadIdx.x;
    const int b    = blockIdx.x;
    const int base = tid * CPT;

    // per-thread register state for owned columns [base, base+8)
    float4 o[CPT];
    double sh[CPT];
    double vv[CPT];

    #pragma unroll
    for (int kk = 0; kk < CPT; ++kk) {
        o[kk]  = reinterpret_cast<const float4*>(outputs)[b * NQ + base + kk];
        vv[kk] = 0.0;
    }
    for (int k = tid; k < NQ; k += BT) row4col_[k] = -1;
    if (tid < NTGT) {
        u_[tid] = 0.0;
        col4row_[tid] = -1;
        tgt_[tid] = reinterpret_cast<const float4*>(targets)[b * NTGT + tid];
    }
    __syncthreads();

    int parity = 0;

    for (int cur = 0; cur < NTGT; ++cur) {
        const int rp = cur & 1;
        unsigned rem      = 0xFFu;
        unsigned pendmask = 0u;
        int    i     = cur;
        bool   first = true;
        int    Lns   = 0;
        double minv  = 0.0;
        int    fj    = -1;

        while (true) {
            const double ui = u_[i];
            const float4 g  = tgt_[i];

            double bv = (double)INFINITY;
            int    bi = 0x7fffffff;

            if (first) {
                #pragma unroll
                for (int kk = 0; kk < CPT; ++kk) {
                    float4 oo = o[kk];
                    float  c  = (fabsf(oo.x - g.x) + fabsf(oo.y - g.y)) +
                                (fabsf(oo.z - g.z) + fabsf(oo.w - g.w));
                    double cand = ((minv + (double)c) - ui) - vv[kk];
                    sh[kk] = cand;
                    path_[rp][base + kk] = (unsigned char)i;
                    if (cand < bv) { bv = cand; bi = base + kk; }
                }
            } else {
                #pragma unroll
                for (int kk = 0; kk < CPT; ++kk) {
                    if (rem & (1u << kk)) {
                        float4 oo = o[kk];
                        float  c  = (fabsf(oo.x - g.x) + fabsf(oo.y - g.y)) +
                                    (fabsf(oo.z - g.z) + fabsf(oo.w - g.w));
                        double cand = ((minv + (double)c) - ui) - vv[kk];
                        if (cand < sh[kk]) { sh[kk] = cand; path_[rp][base + kk] = (unsigned char)i; }
                        double s = sh[kk];
                        if (s < bv) { bv = s; bi = base + kk; }
                    }
                }
            }

            // wave-level (min, lowest-index) reduction
            for (int off = 32; off > 0; off >>= 1) {
                double ov = __shfl_down(bv, off);
                int    oi = __shfl_down(bi, off);
                if (ov < bv || (ov == bv && oi < bi)) { bv = ov; bi = oi; }
            }
            if ((tid & 63) == 0) { red_val[parity][tid >> 6] = bv; red_idx[parity][tid >> 6] = bi; }
            __syncthreads();

            // all threads finish the reduction redundantly
            double fv = red_val[parity][0];
            int    jj = red_idx[parity][0];
            #pragma unroll
            for (int w = 1; w < NW; ++w) {
                double ov = red_val[parity][w];
                int    oi = red_idx[parity][w];
                if (ov < fv || (ov == fv && oi < jj)) { fv = ov; jj = oi; }
            }
            parity ^= 1;
            fj   = jj;
            minv = fv;

            const bool owner = ((fj >> 3) == tid);
            if (owner) rem &= ~(1u << (fj & 7));

            int r = row4col_[fj];
            if (r < 0) break;                 // sink found
            // non-sink pick: owner's sh[fj&7] already holds shortest[fj]==fv
            // and is never touched again this row.
            if (owner) pendmask |= (1u << (fj & 7));
            if (tid == 0) { sc_j[Lns] = fj; sc_v[Lns] = fv; }
            Lns++;
            i = r;
            first = false;
        }

        // ---- row end: NO barrier. Everything below is thread-local or
        // tid0-local; publication to other threads is ordered by the next
        // iteration's reduce barrier. ----
        const double dfin = minv;

        // owner v-patches from registers (reference: v[SC] -= minv - shortest;
        // sink term is exactly +0.0 -> skipped)
        #pragma unroll
        for (int kk = 0; kk < CPT; ++kk)
            if (pendmask & (1u << kk)) vv[kk] -= dfin - sh[kk];

        if (tid == 0) {
            // u updates (reference order; row4col_ read pre-augment)
            u_[cur] += dfin;
            for (int e = 0; e < Lns; ++e) {
                int i2 = row4col_[sc_j[e]];
                u_[i2] += dfin - sc_v[e];
            }
            // augment along alternating path (old-parity path buffer)
            int j = fj;
            while (true) {
                int i2 = path_[rp][j];
                row4col_[j] = (short)i2;
                int nj = col4row_[i2];
                col4row_[i2] = (short)j;
                j = nj;
                if (i2 == cur) break;
            }
        }
    }
    __syncthreads();

    // outputs (transposed case): order = argsort(col4row);
    // row_ind = col4row[order]; col_ind = order. Values distinct -> rank by
    // counting smaller values.
    if (tid < NTGT) {
        int val = col4row_[tid];
        int rank = 0;
        for (int k = 0; k < NTGT; ++k) rank += (col4row_[k] < val);
        row_out[b * NTGT + rank] = (float)val;
        col_out[b * NTGT + rank] = (float)tid;
    }
}

extern "C" void kernel_launch(void* const* d_in, const int* in_sizes, int n_in,
                              void* d_out, int out_size, void* d_ws, size_t ws_size,
                              hipStream_t stream) {
    const float* outputs = (const float*)d_in[0];   // [16, 4096, 4]
    const float* targets = (const float*)d_in[1];   // [16, 128, 4]
    float* out = (float*)d_out;                     // C | row_ind | col_ind (as f32)

    hipLaunchKernelGGL(cost_kernel, dim3(CELEMS / 4 / 256), dim3(256), 0, stream,
                       outputs, targets, out);
    hipLaunchKernelGGL(lsa_kernel, dim3(NB), dim3(BT), 0, stream,
                       outputs, targets, out + CELEMS, out + CELEMS + NB * NTGT);
}

// Round 5
// 75.314 us; speedup vs baseline: 8.4007x; 3.6653x over previous
//
#include <hip/hip_runtime.h>
#include <math.h>

#define NB   16
#define NQ   4096
#define NTGT 128
#define CELEMS (NB * NQ * NTGT)

#define BT  512
#define NW  (BT / 64)
#define CPT 8              // columns per thread (NQ / BT)

typedef unsigned long long u64;

// ---------------- cost matrix + per-row (target) min/argmin ----------------
// One thread computes 4 consecutive t for one (b,q); float4 store. Each block
// covers 8 q's x all 128 t's; block-reduces per-row min over its 8 q's and
// atomicMin's a packed (cost_bits<<32 | q) key into rowkey[b*128+t].
// Unsigned min == (min cost, then lowest q) since cost >= 0.
__global__ __launch_bounds__(256) void cost_kernel(
    const float* __restrict__ outputs,
    const float* __restrict__ targets,
    float* __restrict__ C,
    u64*   __restrict__ rowkey)       // [NB*NTGT], pre-memset to 0xFF
{
    __shared__ u64 part[8][NTGT];     // 8 KB
    int idx  = blockIdx.x * 256 + threadIdx.x;   // [0, CELEMS/4)
    int t4   = idx & 31;
    int bq   = idx >> 5;
    int b    = idx >> 17;
    int qloc = threadIdx.x >> 5;                 // 0..7 within block
    float4 o = reinterpret_cast<const float4*>(outputs)[bq];
    const float4* tg = reinterpret_cast<const float4*>(targets) + (b << 7) + (t4 << 2);
    float r[4];
    #pragma unroll
    for (int e = 0; e < 4; ++e) {
        float4 g = tg[e];
        r[e] = (fabsf(o.x - g.x) + fabsf(o.y - g.y)) + (fabsf(o.z - g.z) + fabsf(o.w - g.w));
    }
    reinterpret_cast<float4*>(C)[idx] = make_float4(r[0], r[1], r[2], r[3]);

    int q = bq & (NQ - 1);
    #pragma unroll
    for (int e = 0; e < 4; ++e)
        part[qloc][(t4 << 2) + e] = (((u64)__float_as_uint(r[e])) << 32) | (u64)q;
    __syncthreads();
    int tid = threadIdx.x;
    if (tid < NTGT) {
        u64 k = part[0][tid];
        #pragma unroll
        for (int qq = 1; qq < 8; ++qq) { u64 ov = part[qq][tid]; if (ov < k) k = ov; }
        atomicMin(&rowkey[(b << 7) + tid], k);
    }
}

// ---------------- LSA kernel: row-reduction init + rare augmentation ----------
// One block per batch, transposed problem: 128 rows (targets) x 4096 cols
// (queries). Init: u[i] = rowmin[i], v = 0 (dual feasible, v<=0 respected),
// greedily assign row i -> argmin col (tight edge), lowest row wins conflicts.
// Leftover rows run the exact f64 shortest-augmenting-path (scipy-equivalent)
// from these duals -> provably optimal matching.
__global__ __launch_bounds__(BT, 1) void lsa_kernel(
    const float* __restrict__ outputs,
    const float* __restrict__ targets,
    const u64*   __restrict__ rowkey,
    float* __restrict__ row_out,   // [NB, NTGT] as float
    float* __restrict__ col_out)   // [NB, NTGT] as float
{
    __shared__ float4 tgt_[NTGT];
    __shared__ double u_[NTGT];
    __shared__ int    rowarg_[NTGT];
    __shared__ short  row4col_[NQ];
    __shared__ short  col4row_[NTGT];
    __shared__ unsigned char path_[NQ];
    __shared__ int    sc_j[NTGT];
    __shared__ double sc_v[NTGT];
    __shared__ short  sc_i[NTGT];
    __shared__ double red_val[NW];
    __shared__ int    red_idx[NW];
    __shared__ int    nleft_;
    __shared__ short  left_[NTGT];

    const int tid  = threadIdx.x;
    const int b    = blockIdx.x;
    const int base = tid * CPT;

    // per-thread register state for owned columns [base, base+8)
    float4 o[CPT];
    double sh[CPT];
    double vv[CPT];

    #pragma unroll
    for (int kk = 0; kk < CPT; ++kk) {
        o[kk]  = reinterpret_cast<const float4*>(outputs)[b * NQ + base + kk];
        vv[kk] = 0.0;
    }
    for (int k = tid; k < NQ; k += BT) row4col_[k] = -1;
    if (tid < NTGT) {
        u64 key = rowkey[(b << 7) + tid];
        u_[tid] = (double)__uint_as_float((unsigned)(key >> 32));
        rowarg_[tid] = (int)(key & 0xffffffffu);
        tgt_[tid] = reinterpret_cast<const float4*>(targets)[b * NTGT + tid];
    }
    __syncthreads();

    // greedy claim: row i takes its argmin column; lowest row wins conflicts
    if (tid < NTGT) {
        int j = rowarg_[tid];
        bool won = true;
        for (int i2 = 0; i2 < tid; ++i2)
            if (rowarg_[i2] == j) { won = false; break; }
        col4row_[tid] = won ? (short)j : (short)-1;
        if (won) row4col_[j] = (short)tid;   // winners have distinct j
    }
    __syncthreads();

    if (tid == 0) {
        int n = 0;
        for (int r = 0; r < NTGT; ++r)
            if (col4row_[r] < 0) left_[n++] = r;
        nleft_ = n;
    }
    __syncthreads();
    const int nleft = nleft_;

    // ---- exact shortest-augmenting-path for leftover rows (rare) ----
    for (int li = 0; li < nleft; ++li) {
        const int cur = left_[li];
        unsigned rem      = 0xFFu;
        unsigned pendmask = 0u;
        int    i     = cur;
        bool   first = true;
        int    Lns   = 0;
        double minv  = 0.0;
        int    fj    = -1;

        while (true) {
            const double ui = u_[i];
            const float4 g  = tgt_[i];

            double bv = (double)INFINITY;
            int    bi = 0x7fffffff;

            if (first) {
                #pragma unroll
                for (int kk = 0; kk < CPT; ++kk) {
                    float4 oo = o[kk];
                    float  c  = (fabsf(oo.x - g.x) + fabsf(oo.y - g.y)) +
                                (fabsf(oo.z - g.z) + fabsf(oo.w - g.w));
                    double cand = ((minv + (double)c) - ui) - vv[kk];
                    sh[kk] = cand;
                    path_[base + kk] = (unsigned char)i;
                    if (cand < bv) { bv = cand; bi = base + kk; }
                }
            } else {
                #pragma unroll
                for (int kk = 0; kk < CPT; ++kk) {
                    if (rem & (1u << kk)) {
                        float4 oo = o[kk];
                        float  c  = (fabsf(oo.x - g.x) + fabsf(oo.y - g.y)) +
                                    (fabsf(oo.z - g.z) + fabsf(oo.w - g.w));
                        double cand = ((minv + (double)c) - ui) - vv[kk];
                        if (cand < sh[kk]) { sh[kk] = cand; path_[base + kk] = (unsigned char)i; }
                        double s = sh[kk];
                        if (s < bv) { bv = s; bi = base + kk; }
                    }
                }
            }

            // wave reduce: lane l's columns all < lane l+off's, so strict <
            // keeps the lowest column index on ties
            for (int off = 32; off > 0; off >>= 1) {
                double ov = __shfl_down(bv, off);
                int    oi = __shfl_down(bi, off);
                if (ov < bv) { bv = ov; bi = oi; }
            }
            if ((tid & 63) == 0) { red_val[tid >> 6] = bv; red_idx[tid >> 6] = bi; }
            __syncthreads();

            double fv = red_val[0];
            int    jj = red_idx[0];
            #pragma unroll
            for (int w = 1; w < NW; ++w) {
                double ov = red_val[w];
                if (ov < fv) { fv = ov; jj = red_idx[w]; }
            }
            __syncthreads();   // protects red slot reuse next iteration

            fj   = jj;
            minv = fv;

            const bool owner = ((fj >> 3) == tid);
            if (owner) rem &= ~(1u << (fj & 7));

            int r = row4col_[fj];
            if (r < 0) break;                 // sink found
            if (owner) pendmask |= (1u << (fj & 7));
            if (tid == 0) { sc_j[Lns] = fj; sc_v[Lns] = minv; sc_i[Lns] = (short)r; }
            Lns++;
            i = r;
            first = false;
        }

        // ---- row end ----
        const double dfin = minv;
        #pragma unroll
        for (int kk = 0; kk < CPT; ++kk)
            if (pendmask & (1u << kk)) vv[kk] -= dfin - sh[kk];

        if (tid == 0) {
            u_[cur] += dfin;
            for (int e = 0; e < Lns; ++e)
                u_[sc_i[e]] += dfin - sc_v[e];
            // augment along alternating path
            int j = fj;
            while (true) {
                int i2 = path_[j];
                row4col_[j] = (short)i2;
                int nj = col4row_[i2];
                col4row_[i2] = (short)j;
                j = nj;
                if (i2 == cur) break;
            }
        }
        __syncthreads();
    }

    // outputs (transposed case): order = argsort(col4row);
    // row_ind = col4row[order]; col_ind = order. Values distinct -> rank by
    // counting smaller values.
    if (tid < NTGT) {
        int val = col4row_[tid];
        int rank = 0;
        for (int k = 0; k < NTGT; ++k) rank += (col4row_[k] < val);
        row_out[b * NTGT + rank] = (float)val;
        col_out[b * NTGT + rank] = (float)tid;
    }
}

extern "C" void kernel_launch(void* const* d_in, const int* in_sizes, int n_in,
                              void* d_out, int out_size, void* d_ws, size_t ws_size,
                              hipStream_t stream) {
    const float* outputs = (const float*)d_in[0];   // [16, 4096, 4]
    const float* targets = (const float*)d_in[1];   // [16, 128, 4]
    float* out = (float*)d_out;                     // C | row_ind | col_ind (as f32)

    u64* rowkey = (u64*)d_ws;                       // 16 KB

    hipMemsetAsync(rowkey, 0xFF, NB * NTGT * sizeof(u64), stream);
    hipLaunchKernelGGL(cost_kernel, dim3(CELEMS / 4 / 256), dim3(256), 0, stream,
                       outputs, targets, out, rowkey);
    hipLaunchKernelGGL(lsa_kernel, dim3(NB), dim3(BT), 0, stream,
                       outputs, targets, rowkey,
                       out + CELEMS, out + CELEMS + NB * NTGT);
}

// Round 6
// 56.346 us; speedup vs baseline: 11.2288x; 1.3366x over previous
//
#include <hip/hip_runtime.h>
#include <math.h>

#define NB   16
#define NQ   4096
#define NTGT 128
#define CELEMS (NB * NQ * NTGT)

#define BT  512
#define NW  (BT / 64)
#define CPT 8              // columns per thread in lsa (NQ / BT)
#define NGRP 32            // rowmin groups per batch (4 cost-blocks each)

typedef unsigned long long u64;

// ---------------- cost matrix + per-row (target) min/argmin ----------------
// Grid 2048 x 256. Each thread handles 4 q's x 4 t's (16 cells); float4 loads
// and stores are fully coalesced. Block covers 32 q x 128 t; per-row key
// (cost_bits<<32 | q, u64-min == min cost then lowest q) is reduced in LDS,
// then atomicMin'd into the block's GROUP slot (4 blocks/group -> chain <= 4).
__global__ __launch_bounds__(256) void cost_kernel(
    const float* __restrict__ outputs,
    const float* __restrict__ targets,
    float* __restrict__ C,
    u64*   __restrict__ rowkey2)      // [NB][NGRP][NTGT], pre-memset 0xFF
{
    __shared__ u64 part[8][NTGT];     // 8 KB
    const int tid  = threadIdx.x;
    const int idx0 = blockIdx.x * 1024 + tid;    // quad-cell base
    const int t4   = tid & 31;
    const int qloc = tid >> 5;
    const int b    = blockIdx.x >> 7;            // 128 blocks per batch
    const int blk  = blockIdx.x & 127;

    const float4* tg = reinterpret_cast<const float4*>(targets) + (b << 7) + (t4 << 2);
    float4 g[4];
    #pragma unroll
    for (int f = 0; f < 4; ++f) g[f] = tg[f];

    u64 keymin[4] = {~0ull, ~0ull, ~0ull, ~0ull};

    #pragma unroll
    for (int e = 0; e < 4; ++e) {
        int idx = idx0 + 256 * e;
        int bq  = idx >> 5;
        float4 o = reinterpret_cast<const float4*>(outputs)[bq];
        u64 q = (u64)(unsigned)(bq & (NQ - 1));
        float r[4];
        #pragma unroll
        for (int f = 0; f < 4; ++f) {
            float4 gg = g[f];
            r[f] = (fabsf(o.x - gg.x) + fabsf(o.y - gg.y)) +
                   (fabsf(o.z - gg.z) + fabsf(o.w - gg.w));
            u64 key = (((u64)__float_as_uint(r[f])) << 32) | q;
            if (key < keymin[f]) keymin[f] = key;
        }
        reinterpret_cast<float4*>(C)[idx] = make_float4(r[0], r[1], r[2], r[3]);
    }

    #pragma unroll
    for (int f = 0; f < 4; ++f) part[qloc][(t4 << 2) + f] = keymin[f];
    __syncthreads();

    if (tid < NTGT) {
        u64 k = part[0][tid];
        #pragma unroll
        for (int qq = 1; qq < 8; ++qq) { u64 ov = part[qq][tid]; if (ov < k) k = ov; }
        atomicMin(&rowkey2[(((size_t)b * NGRP) + (blk >> 2)) * NTGT + tid], k);
    }
}

// ---------------- LSA kernel: row-reduction init + rare augmentation ----------
// One block per batch, transposed problem: 128 rows (targets) x 4096 cols
// (queries). Init: u[i] = rowmin[i], v = 0 (dual feasible), greedily assign
// row i -> argmin col (tight edge), lowest row wins conflicts. Leftover rows
// run the exact f64 shortest-augmenting-path (scipy-equivalent) from these
// duals -> provably optimal matching.
__global__ __launch_bounds__(BT, 1) void lsa_kernel(
    const float* __restrict__ outputs,
    const float* __restrict__ targets,
    const u64*   __restrict__ rowkey2,
    float* __restrict__ row_out,   // [NB, NTGT] as float
    float* __restrict__ col_out)   // [NB, NTGT] as float
{
    __shared__ float4 tgt_[NTGT];
    __shared__ double u_[NTGT];
    __shared__ int    rowarg_[NTGT];
    __shared__ u64    red2_[4][NTGT];
    __shared__ short  row4col_[NQ];
    __shared__ short  col4row_[NTGT];
    __shared__ unsigned char path_[NQ];
    __shared__ int    sc_j[NTGT];
    __shared__ double sc_v[NTGT];
    __shared__ short  sc_i[NTGT];
    __shared__ double red_val[NW];
    __shared__ int    red_idx[NW];
    __shared__ int    nleft_;
    __shared__ short  left_[NTGT];

    const int tid  = threadIdx.x;
    const int b    = blockIdx.x;
    const int base = tid * CPT;

    // per-thread register state for owned columns [base, base+8)
    float4 o[CPT];
    double sh[CPT];
    double vv[CPT];

    #pragma unroll
    for (int kk = 0; kk < CPT; ++kk) {
        o[kk]  = reinterpret_cast<const float4*>(outputs)[b * NQ + base + kk];
        vv[kk] = 0.0;
    }
    for (int k = tid; k < NQ; k += BT) row4col_[k] = -1;

    // reduce the 32 group keys per row (coalesced: consecutive lanes -> consecutive t)
    {
        const int t = tid & 127, s = tid >> 7;
        const u64* rk = rowkey2 + (size_t)b * NGRP * NTGT;
        u64 k = ~0ull;
        #pragma unroll
        for (int gg = 0; gg < NGRP / 4; ++gg) {
            u64 ov = rk[(s * (NGRP / 4) + gg) * NTGT + t];
            if (ov < k) k = ov;
        }
        red2_[s][t] = k;
    }
    __syncthreads();

    if (tid < NTGT) {
        u64 key = red2_[0][tid];
        #pragma unroll
        for (int s = 1; s < 4; ++s) { u64 ov = red2_[s][tid]; if (ov < key) key = ov; }
        u_[tid] = (double)__uint_as_float((unsigned)(key >> 32));
        rowarg_[tid] = (int)(key & 0xffffffffu);
        tgt_[tid] = reinterpret_cast<const float4*>(targets)[b * NTGT + tid];
    }
    __syncthreads();

    // greedy claim: row i takes its argmin column; lowest row wins conflicts
    if (tid < NTGT) {
        int j = rowarg_[tid];
        bool won = true;
        for (int i2 = 0; i2 < tid; ++i2)
            if (rowarg_[i2] == j) { won = false; break; }
        col4row_[tid] = won ? (short)j : (short)-1;
        if (won) row4col_[j] = (short)tid;   // winners have distinct j
    }
    __syncthreads();

    if (tid == 0) {
        int n = 0;
        for (int r = 0; r < NTGT; ++r)
            if (col4row_[r] < 0) left_[n++] = r;
        nleft_ = n;
    }
    __syncthreads();
    const int nleft = nleft_;

    // ---- exact shortest-augmenting-path for leftover rows (rare) ----
    for (int li = 0; li < nleft; ++li) {
        const int cur = left_[li];
        unsigned rem      = 0xFFu;
        unsigned pendmask = 0u;
        int    i     = cur;
        bool   first = true;
        int    Lns   = 0;
        double minv  = 0.0;
        int    fj    = -1;

        while (true) {
            const double ui = u_[i];
            const float4 g  = tgt_[i];

            double bv = (double)INFINITY;
            int    bi = 0x7fffffff;

            if (first) {
                #pragma unroll
                for (int kk = 0; kk < CPT; ++kk) {
                    float4 oo = o[kk];
                    float  c  = (fabsf(oo.x - g.x) + fabsf(oo.y - g.y)) +
                                (fabsf(oo.z - g.z) + fabsf(oo.w - g.w));
                    double cand = ((minv + (double)c) - ui) - vv[kk];
                    sh[kk] = cand;
                    path_[base + kk] = (unsigned char)i;
                    if (cand < bv) { bv = cand; bi = base + kk; }
                }
            } else {
                #pragma unroll
                for (int kk = 0; kk < CPT; ++kk) {
                    if (rem & (1u << kk)) {
                        float4 oo = o[kk];
                        float  c  = (fabsf(oo.x - g.x) + fabsf(oo.y - g.y)) +
                                    (fabsf(oo.z - g.z) + fabsf(oo.w - g.w));
                        double cand = ((minv + (double)c) - ui) - vv[kk];
                        if (cand < sh[kk]) { sh[kk] = cand; path_[base + kk] = (unsigned char)i; }
                        double s = sh[kk];
                        if (s < bv) { bv = s; bi = base + kk; }
                    }
                }
            }

            // wave reduce: lane l's columns all < lane l+off's, so strict <
            // keeps the lowest column index on ties
            for (int off = 32; off > 0; off >>= 1) {
                double ov = __shfl_down(bv, off);
                int    oi = __shfl_down(bi, off);
                if (ov < bv) { bv = ov; bi = oi; }
            }
            if ((tid & 63) == 0) { red_val[tid >> 6] = bv; red_idx[tid >> 6] = bi; }
            __syncthreads();

            double fv = red_val[0];
            int    jj = red_idx[0];
            #pragma unroll
            for (int w = 1; w < NW; ++w) {
                double ov = red_val[w];
                if (ov < fv) { fv = ov; jj = red_idx[w]; }
            }
            __syncthreads();   // protects red slot reuse next iteration

            fj   = jj;
            minv = fv;

            const bool owner = ((fj >> 3) == tid);
            if (owner) rem &= ~(1u << (fj & 7));

            int r = row4col_[fj];
            if (r < 0) break;                 // sink found
            if (owner) pendmask |= (1u << (fj & 7));
            if (tid == 0) { sc_j[Lns] = fj; sc_v[Lns] = minv; sc_i[Lns] = (short)r; }
            Lns++;
            i = r;
            first = false;
        }

        // ---- row end ----
        const double dfin = minv;
        #pragma unroll
        for (int kk = 0; kk < CPT; ++kk)
            if (pendmask & (1u << kk)) vv[kk] -= dfin - sh[kk];

        if (tid == 0) {
            u_[cur] += dfin;
            for (int e = 0; e < Lns; ++e)
                u_[sc_i[e]] += dfin - sc_v[e];
            // augment along alternating path
            int j = fj;
            while (true) {
                int i2 = path_[j];
                row4col_[j] = (short)i2;
                int nj = col4row_[i2];
                col4row_[i2] = (short)j;
                j = nj;
                if (i2 == cur) break;
            }
        }
        __syncthreads();
    }

    // outputs (transposed case): order = argsort(col4row);
    // row_ind = col4row[order]; col_ind = order. Values distinct -> rank by
    // counting smaller values.
    if (tid < NTGT) {
        int val = col4row_[tid];
        int rank = 0;
        for (int k = 0; k < NTGT; ++k) rank += (col4row_[k] < val);
        row_out[b * NTGT + rank] = (float)val;
        col_out[b * NTGT + rank] = (float)tid;
    }
}

extern "C" void kernel_launch(void* const* d_in, const int* in_sizes, int n_in,
                              void* d_out, int out_size, void* d_ws, size_t ws_size,
                              hipStream_t stream) {
    const float* outputs = (const float*)d_in[0];   // [16, 4096, 4]
    const float* targets = (const float*)d_in[1];   // [16, 128, 4]
    float* out = (float*)d_out;                     // C | row_ind | col_ind (as f32)

    u64* rowkey2 = (u64*)d_ws;                      // NB*NGRP*NTGT*8 = 512 KB

    hipMemsetAsync(rowkey2, 0xFF, (size_t)NB * NGRP * NTGT * sizeof(u64), stream);
    hipLaunchKernelGGL(cost_kernel, dim3(CELEMS / 16 / 256), dim3(256), 0, stream,
                       outputs, targets, out, rowkey2);
    hipLaunchKernelGGL(lsa_kernel, dim3(NB), dim3(BT), 0, stream,
                       outputs, targets, rowkey2,
                       out + CELEMS, out + CELEMS + NB * NTGT);
}

// Round 7
// 52.328 us; speedup vs baseline: 12.0910x; 1.0768x over previous
//
#include <hip/hip_runtime.h>
#include <math.h>

#define NB   16
#define NQ   4096
#define NTGT 128
#define CELEMS (NB * NQ * NTGT)

#define BT  512
#define NW  (BT / 64)
#define CPT 8              // columns per thread in lsa (NQ / BT)
#define NBLK 128           // cost blocks per batch == rowkey slots per batch

typedef unsigned long long u64;

// ---------------- cost matrix + per-row (target) min/argmin ----------------
// Grid 2048 x 256. Each thread handles 4 q's x 4 t's (16 cells); float4 loads
// and stores fully coalesced. Block covers 32 q x 128 t; per-row key
// (cost_bits<<32 | q, u64-min == min cost then lowest q) is reduced in LDS,
// then PLAIN-stored to the block's own slot rowkey2[b][blk][t] — no atomics,
// no pre-initialization.
__global__ __launch_bounds__(256) void cost_kernel(
    const float* __restrict__ outputs,
    const float* __restrict__ targets,
    float* __restrict__ C,
    u64*   __restrict__ rowkey2)      // [NB][NBLK][NTGT]
{
    __shared__ u64 part[8][NTGT];     // 8 KB
    const int tid  = threadIdx.x;
    const int idx0 = blockIdx.x * 1024 + tid;    // quad-cell base
    const int t4   = tid & 31;
    const int qloc = tid >> 5;
    const int b    = blockIdx.x >> 7;            // 128 blocks per batch
    const int blk  = blockIdx.x & (NBLK - 1);

    const float4* tg = reinterpret_cast<const float4*>(targets) + (b << 7) + (t4 << 2);
    float4 g[4];
    #pragma unroll
    for (int f = 0; f < 4; ++f) g[f] = tg[f];

    u64 keymin[4] = {~0ull, ~0ull, ~0ull, ~0ull};

    #pragma unroll
    for (int e = 0; e < 4; ++e) {
        int idx = idx0 + 256 * e;
        int bq  = idx >> 5;
        float4 o = reinterpret_cast<const float4*>(outputs)[bq];
        u64 q = (u64)(unsigned)(bq & (NQ - 1));
        float r[4];
        #pragma unroll
        for (int f = 0; f < 4; ++f) {
            float4 gg = g[f];
            r[f] = (fabsf(o.x - gg.x) + fabsf(o.y - gg.y)) +
                   (fabsf(o.z - gg.z) + fabsf(o.w - gg.w));
            u64 key = (((u64)__float_as_uint(r[f])) << 32) | q;
            if (key < keymin[f]) keymin[f] = key;
        }
        reinterpret_cast<float4*>(C)[idx] = make_float4(r[0], r[1], r[2], r[3]);
    }

    #pragma unroll
    for (int f = 0; f < 4; ++f) part[qloc][(t4 << 2) + f] = keymin[f];
    __syncthreads();

    if (tid < NTGT) {
        u64 k = part[0][tid];
        #pragma unroll
        for (int qq = 1; qq < 8; ++qq) { u64 ov = part[qq][tid]; if (ov < k) k = ov; }
        rowkey2[(((size_t)b * NBLK) + blk) * NTGT + tid] = k;
    }
}

// ---------------- LSA kernel: row-reduction init + rare augmentation ----------
// One block per batch, transposed problem: 128 rows (targets) x 4096 cols
// (queries). Init: u[i] = rowmin[i], v = 0 (dual feasible), greedily assign
// row i -> argmin col (tight edge), lowest row wins conflicts. Leftover rows
// run the exact f64 shortest-augmenting-path (scipy-equivalent) from these
// duals -> provably optimal matching.
__global__ __launch_bounds__(BT, 1) void lsa_kernel(
    const float* __restrict__ outputs,
    const float* __restrict__ targets,
    const u64*   __restrict__ rowkey2,
    float* __restrict__ row_out,   // [NB, NTGT] as float
    float* __restrict__ col_out)   // [NB, NTGT] as float
{
    __shared__ float4 tgt_[NTGT];
    __shared__ double u_[NTGT];
    __shared__ int    rowarg_[NTGT];
    __shared__ u64    red2_[4][NTGT];
    __shared__ short  row4col_[NQ];
    __shared__ short  col4row_[NTGT];
    __shared__ unsigned char path_[NQ];
    __shared__ int    sc_j[NTGT];
    __shared__ double sc_v[NTGT];
    __shared__ short  sc_i[NTGT];
    __shared__ double red_val[NW];
    __shared__ int    red_idx[NW];
    __shared__ int    nleft_;
    __shared__ short  left_[NTGT];

    const int tid  = threadIdx.x;
    const int b    = blockIdx.x;
    const int base = tid * CPT;

    // per-thread register state for owned columns [base, base+8)
    float4 o[CPT];
    double sh[CPT];
    double vv[CPT];

    #pragma unroll
    for (int kk = 0; kk < CPT; ++kk) {
        o[kk]  = reinterpret_cast<const float4*>(outputs)[b * NQ + base + kk];
        vv[kk] = 0.0;
    }
    for (int k = tid; k < NQ; k += BT) row4col_[k] = -1;

    // reduce the 128 slot keys per row (coalesced: consecutive lanes -> consecutive t)
    {
        const int t = tid & 127, s = tid >> 7;            // 4 slices x 32 slots
        const u64* rk = rowkey2 + (size_t)b * NBLK * NTGT;
        u64 k = ~0ull;
        #pragma unroll
        for (int gg = 0; gg < NBLK / 4; ++gg) {
            u64 ov = rk[(s * (NBLK / 4) + gg) * NTGT + t];
            if (ov < k) k = ov;
        }
        red2_[s][t] = k;
    }
    __syncthreads();

    if (tid < NTGT) {
        u64 key = red2_[0][tid];
        #pragma unroll
        for (int s = 1; s < 4; ++s) { u64 ov = red2_[s][tid]; if (ov < key) key = ov; }
        u_[tid] = (double)__uint_as_float((unsigned)(key >> 32));
        rowarg_[tid] = (int)(key & 0xffffffffu);
        tgt_[tid] = reinterpret_cast<const float4*>(targets)[b * NTGT + tid];
    }
    __syncthreads();

    // greedy claim: row i takes its argmin column; lowest row wins conflicts
    if (tid < NTGT) {
        int j = rowarg_[tid];
        bool won = true;
        for (int i2 = 0; i2 < tid; ++i2)
            if (rowarg_[i2] == j) { won = false; break; }
        col4row_[tid] = won ? (short)j : (short)-1;
        if (won) row4col_[j] = (short)tid;   // winners have distinct j
    }
    __syncthreads();

    if (tid == 0) {
        int n = 0;
        for (int r = 0; r < NTGT; ++r)
            if (col4row_[r] < 0) left_[n++] = r;
        nleft_ = n;
    }
    __syncthreads();
    const int nleft = nleft_;

    // ---- exact shortest-augmenting-path for leftover rows (rare) ----
    for (int li = 0; li < nleft; ++li) {
        const int cur = left_[li];
        unsigned rem      = 0xFFu;
        unsigned pendmask = 0u;
        int    i     = cur;
        bool   first = true;
        int    Lns   = 0;
        double minv  = 0.0;
        int    fj    = -1;

        while (true) {
            const double ui = u_[i];
            const float4 g  = tgt_[i];

            double bv = (double)INFINITY;
            int    bi = 0x7fffffff;

            if (first) {
                #pragma unroll
                for (int kk = 0; kk < CPT; ++kk) {
                    float4 oo = o[kk];
                    float  c  = (fabsf(oo.x - g.x) + fabsf(oo.y - g.y)) +
                                (fabsf(oo.z - g.z) + fabsf(oo.w - g.w));
                    double cand = ((minv + (double)c) - ui) - vv[kk];
                    sh[kk] = cand;
                    path_[base + kk] = (unsigned char)i;
                    if (cand < bv) { bv = cand; bi = base + kk; }
                }
            } else {
                #pragma unroll
                for (int kk = 0; kk < CPT; ++kk) {
                    if (rem & (1u << kk)) {
                        float4 oo = o[kk];
                        float  c  = (fabsf(oo.x - g.x) + fabsf(oo.y - g.y)) +
                                    (fabsf(oo.z - g.z) + fabsf(oo.w - g.w));
                        double cand = ((minv + (double)c) - ui) - vv[kk];
                        if (cand < sh[kk]) { sh[kk] = cand; path_[base + kk] = (unsigned char)i; }
                        double s = sh[kk];
                        if (s < bv) { bv = s; bi = base + kk; }
                    }
                }
            }

            // wave reduce: lane l's columns all < lane l+off's, so strict <
            // keeps the lowest column index on ties
            for (int off = 32; off > 0; off >>= 1) {
                double ov = __shfl_down(bv, off);
                int    oi = __shfl_down(bi, off);
                if (ov < bv) { bv = ov; bi = oi; }
            }
            if ((tid & 63) == 0) { red_val[tid >> 6] = bv; red_idx[tid >> 6] = bi; }
            __syncthreads();

            double fv = red_val[0];
            int    jj = red_idx[0];
            #pragma unroll
            for (int w = 1; w < NW; ++w) {
                double ov = red_val[w];
                if (ov < fv) { fv = ov; jj = red_idx[w]; }
            }
            __syncthreads();   // protects red slot reuse next iteration

            fj   = jj;
            minv = fv;

            const bool owner = ((fj >> 3) == tid);
            if (owner) rem &= ~(1u << (fj & 7));

            int r = row4col_[fj];
            if (r < 0) break;                 // sink found
            if (owner) pendmask |= (1u << (fj & 7));
            if (tid == 0) { sc_j[Lns] = fj; sc_v[Lns] = minv; sc_i[Lns] = (short)r; }
            Lns++;
            i = r;
            first = false;
        }

        // ---- row end ----
        const double dfin = minv;
        #pragma unroll
        for (int kk = 0; kk < CPT; ++kk)
            if (pendmask & (1u << kk)) vv[kk] -= dfin - sh[kk];

        if (tid == 0) {
            u_[cur] += dfin;
            for (int e = 0; e < Lns; ++e)
                u_[sc_i[e]] += dfin - sc_v[e];
            // augment along alternating path
            int j = fj;
            while (true) {
                int i2 = path_[j];
                row4col_[j] = (short)i2;
                int nj = col4row_[i2];
                col4row_[i2] = (short)j;
                j = nj;
                if (i2 == cur) break;
            }
        }
        __syncthreads();
    }

    // outputs (transposed case): order = argsort(col4row);
    // row_ind = col4row[order]; col_ind = order. Values distinct -> rank by
    // counting smaller values.
    if (tid < NTGT) {
        int val = col4row_[tid];
        int rank = 0;
        for (int k = 0; k < NTGT; ++k) rank += (col4row_[k] < val);
        row_out[b * NTGT + rank] = (float)val;
        col_out[b * NTGT + rank] = (float)tid;
    }
}

extern "C" void kernel_launch(void* const* d_in, const int* in_sizes, int n_in,
                              void* d_out, int out_size, void* d_ws, size_t ws_size,
                              hipStream_t stream) {
    const float* outputs = (const float*)d_in[0];   // [16, 4096, 4]
    const float* targets = (const float*)d_in[1];   // [16, 128, 4]
    float* out = (float*)d_out;                     // C | row_ind | col_ind (as f32)

    u64* rowkey2 = (u64*)d_ws;                      // NB*NBLK*NTGT*8 = 2 MB

    hipLaunchKernelGGL(cost_kernel, dim3(CELEMS / 16 / 256), dim3(256), 0, stream,
                       outputs, targets, out, rowkey2);
    hipLaunchKernelGGL(lsa_kernel, dim3(NB), dim3(BT), 0, stream,
                       outputs, targets, rowkey2,
                       out + CELEMS, out + CELEMS + NB * NTGT);
}